// Round 5
// baseline (407.910 us; speedup 1.0000x reference)
//
#include <hip/hip_runtime.h>

#define EPS_F 1e-5f

// DPP move with explicit 'old' (value for invalid/masked lanes; bound_ctrl=false).
#define DPPF(old, x, ctrl, rm, bm) \
  __int_as_float(__builtin_amdgcn_update_dpp(__float_as_int(old), __float_as_int(x), ctrl, rm, bm, false))

// Wave shift-right-by-1 (gfx9/CDNA DPP 0x138): lane l <- lane l-1; lane 0
// takes 'old'. VERIFIED: round-4 passing kernel depends on it (T and Pex).
#define WAVE_SR1(old, x) DPPF(old, x, 0x138, 0xf, 0xf)

// Canonical gfx9 wave64 inclusive scans (VALU pipe, no LDS).
__device__ __forceinline__ float scan_add64(float x) {
  x += DPPF(0.0f, x, 0x111, 0xf, 0xf);
  x += DPPF(0.0f, x, 0x112, 0xf, 0xf);
  x += DPPF(0.0f, x, 0x114, 0xf, 0xf);
  x += DPPF(0.0f, x, 0x118, 0xf, 0xf);
  x += DPPF(0.0f, x, 0x142, 0xa, 0xf);
  x += DPPF(0.0f, x, 0x143, 0xc, 0xf);
  return x;
}
__device__ __forceinline__ float scan_mul64(float x) {
  x *= DPPF(1.0f, x, 0x111, 0xf, 0xf);
  x *= DPPF(1.0f, x, 0x112, 0xf, 0xf);
  x *= DPPF(1.0f, x, 0x114, 0xf, 0xf);
  x *= DPPF(1.0f, x, 0x118, 0xf, 0xf);
  x *= DPPF(1.0f, x, 0x142, 0xa, 0xf);
  x *= DPPF(1.0f, x, 0x143, 0xc, 0xf);
  return x;
}
__device__ __forceinline__ float wave_total(float x) {
  float s = scan_add64(x);
  return __int_as_float(__builtin_amdgcn_readlane(__float_as_int(s), 63));
}

// Per-ray state processed by one wave. Two instances per wave give the SIMD a
// second independent instruction stream: rocprof r4 showed VALUBusy=64% with a
// 36% bubble from correlated serial chains (DPP scans, LDS binary searches);
// in-wave ILP fills it without changing per-ray arithmetic at all.
__global__ __launch_bounds__(256) void nerf_volrend(
    const float* __restrict__ rays,
    const float* __restrict__ sigc,
    const float* __restrict__ rgbc,
    const float* __restrict__ sigf,
    const float* __restrict__ rgbf,
    float* __restrict__ out, int n_rays)
{
  const int wave = threadIdx.x >> 6;
  const int lane = threadIdx.x & 63;
  const int rayA = (blockIdx.x << 3) + wave;      // 8 rays per block
  const int rayB = rayA + 4;

  // Wave-private LDS slices (A: [wave], B: [wave+4]); no __syncthreads anywhere.
  __shared__ float s_cdf[8][64];
  __shared__ int   s_cc [8][64];
  __shared__ float s_zcb[8][128];
  const int ia = wave, ib = wave + 4;

  const float nearA = rays[rayA*8 + 6], farA = rays[rayA*8 + 7];
  const float nearB = rays[rayB*8 + 6], farB = rays[rayB*8 + 7];

  // Issue ALL global loads up front (both rays): latency hides under compute.
  float sgvA = sigc[rayA*64 + lane];
  float sgvB = sigc[rayB*64 + lane];
  const float r0A = rgbc[rayA*192 + lane*3 + 0];
  const float r1A = rgbc[rayA*192 + lane*3 + 1];
  const float r2A = rgbc[rayA*192 + lane*3 + 2];
  const float r0B = rgbc[rayB*192 + lane*3 + 0];
  const float r1B = rgbc[rayB*192 + lane*3 + 1];
  const float r2B = rgbc[rayB*192 + lane*3 + 2];
  const float2 sgfA = ((const float2*)(sigf + (size_t)rayA*128))[lane];
  const float2 sgfB = ((const float2*)(sigf + (size_t)rayB*128))[lane];
  const float* rbA = rgbf + (size_t)rayA*384 + lane*6;
  const float* rbB = rgbf + (size_t)rayB*384 + lane*6;
  const float2 cA0 = *(const float2*)(rbA + 0);
  const float2 cA1 = *(const float2*)(rbA + 2);
  const float2 cA2 = *(const float2*)(rbA + 4);
  const float2 cB0 = *(const float2*)(rbB + 0);
  const float2 cB1 = *(const float2*)(rbB + 2);
  const float2 cB2 = *(const float2*)(rbB + 4);

  // ---------------- coarse composite ----------------
  const float t  = (float)lane * 0.015625f;
  const float tn = (float)(lane + 1) * 0.015625f;
  const float zA     = nearA * (1.0f - t)  + farA * t;
  const float zB     = nearB * (1.0f - t)  + farB * t;
  const float znxA   = nearA * (1.0f - tn) + farA * tn;
  const float znxB   = nearB * (1.0f - tn) + farB * tn;
  const float dltA = (lane == 63) ? 1e10f : (znxA - zA);
  const float dltB = (lane == 63) ? 1e10f : (znxB - zB);
  sgvA = fmaxf(sgvA, 0.0f);
  sgvB = fmaxf(sgvB, 0.0f);
  const float aA  = 1.0f - __expf(-dltA * sgvA);
  const float aB  = 1.0f - __expf(-dltB * sgvB);
  const float shA = 1.0f - aA + 1e-10f;
  const float shB = 1.0f - aB + 1e-10f;

  const float pinA = scan_mul64(shA);
  const float pinB = scan_mul64(shB);
  const float TA   = WAVE_SR1(1.0f, pinA);
  const float TB   = WAVE_SR1(1.0f, pinB);
  const float wA   = aA * TA;
  const float wB   = aB * TB;

  const float rwA = scan_add64(wA * r0A);
  const float rwB = scan_add64(wB * r0B);
  const float gwA = scan_add64(wA * r1A);
  const float gwB = scan_add64(wB * r1B);
  const float bwA = scan_add64(wA * r2A);
  const float bwB = scan_add64(wB * r2B);
  const float dwA = scan_add64(wA * zA);
  const float dwB = scan_add64(wB * zB);

  if (lane == 63) {
    // Telescope identity: sum(w) = 1 - prod(sh) + O(1e-8) (1e-10 guard terms);
    // no branch consumes ws downstream -> safe, saves a full scan per ray.
    const float wsA = 1.0f - pinA;
    const float wsB = 1.0f - pinB;
    out[rayA*3 + 0]      = rwA + 1.0f - wsA;
    out[rayA*3 + 1]      = gwA + 1.0f - wsA;
    out[rayA*3 + 2]      = bwA + 1.0f - wsA;
    out[n_rays*3 + rayA] = wsA;
    out[n_rays*4 + rayA] = dwA + (1.0f - wsA) * farA;
    out[rayB*3 + 0]      = rwB + 1.0f - wsB;
    out[rayB*3 + 1]      = gwB + 1.0f - wsB;
    out[rayB*3 + 2]      = bwB + 1.0f - wsB;
    out[n_rays*3 + rayB] = wsB;
    out[n_rays*4 + rayB] = dwB + (1.0f - wsB) * farB;
  }

  // ---------------- sample_fine (inverse-CDF) -- r4-verbatim per ray --------
  const float wnxA = __shfl_down(wA, 1);
  const float wnxB = __shfl_down(wB, 1);
  const float wpA  = (lane < 62) ? (wnxA + EPS_F) : 0.0f;
  const float wpB  = (lane < 62) ? (wnxB + EPS_F) : 0.0f;
  const float wpsA = wave_total(wpA);
  const float wpsB = wave_total(wpB);
  const float csA  = scan_add64(wpA / wpsA);
  const float csB  = scan_add64(wpB / wpsB);

  if (lane < 62) { s_cdf[ia][lane + 1] = csA; s_cdf[ib][lane + 1] = csB; }
  if (lane == 0) { s_cdf[ia][0] = 0.0f;       s_cdf[ib][0] = 0.0f; }

  const float* cdfA = s_cdf[ia];
  const float* cdfB = s_cdf[ib];
  const float u = (lane == 63) ? 1.0f : (float)lane * (1.0f / 63.0f);
  int posA = 0, posB = 0;
  #pragma unroll
  for (int stp = 32; stp; stp >>= 1) {
    int npA = posA + stp, npB = posB + stp;
    if (npA <= 63 && cdfA[npA - 1] <= u) posA = npA;
    if (npB <= 63 && cdfB[npB - 1] <= u) posB = npB;
  }
  const int belA = max(posA - 1, 0), abvA = min(posA, 62);
  const int belB = max(posB - 1, 0), abvB = min(posB, 62);
  const float cbA = cdfA[belA], caA = cdfA[abvA];
  const float cbB = cdfB[belB], caB = cdfB[abvB];

  const float tbA  = (float)belA * 0.015625f, tb1A = (float)(belA + 1) * 0.015625f;
  const float taA  = (float)abvA * 0.015625f, ta1A = (float)(abvA + 1) * 0.015625f;
  const float tbB  = (float)belB * 0.015625f, tb1B = (float)(belB + 1) * 0.015625f;
  const float taB  = (float)abvB * 0.015625f, ta1B = (float)(abvB + 1) * 0.015625f;
  const float binbA = 0.5f * ((nearA*(1.0f-tbA) + farA*tbA) + (nearA*(1.0f-tb1A) + farA*tb1A));
  const float binaA = 0.5f * ((nearA*(1.0f-taA) + farA*taA) + (nearA*(1.0f-ta1A) + farA*ta1A));
  const float binbB = 0.5f * ((nearB*(1.0f-tbB) + farB*tbB) + (nearB*(1.0f-tb1B) + farB*tb1B));
  const float binaB = 0.5f * ((nearB*(1.0f-taB) + farB*taB) + (nearB*(1.0f-ta1B) + farB*ta1B));
  float dnA = caA - cbA; if (dnA < EPS_F) dnA = 1.0f;
  float dnB = caB - cbB; if (dnB < EPS_F) dnB = 1.0f;
  const float zfA = binbA + (u - cbA) / dnA * (binaA - binbA);
  const float zfB = binbB + (u - cbB) / dnB * (binaB - binbB);

  // ---------------- merge via ranks (uniform coarse grid) -------------------
  const float invsA = 64.0f / (farA - nearA);
  const float invsB = 64.0f / (farB - nearB);
  int ccA = (int)floorf((zfA - nearA) * invsA) + 1;
  int ccB = (int)floorf((zfB - nearB) * invsB) + 1;
  ccA = min(max(ccA, 0), 64);
  ccB = min(max(ccB, 0), 64);
  s_cc[ia][lane] = ccA;
  s_cc[ib][lane] = ccB;
  s_zcb[ia][lane + ccA] = zfA;
  s_zcb[ib][lane + ccB] = zfB;

  const int* cclA = s_cc[ia];
  const int* cclB = s_cc[ib];
  int cfA = 0, cfB = 0;
  #pragma unroll
  for (int stp = 64; stp; stp >>= 1) {
    int npA = cfA + stp, npB = cfB + stp;
    if (npA <= 64 && cclA[npA - 1] <= lane) cfA = npA;
    if (npB <= 64 && cclB[npB - 1] <= lane) cfB = npB;
  }
  s_zcb[ia][lane + cfA] = zA;
  s_zcb[ib][lane + cfB] = zB;

  // ---------------- fine composite (2 samples / lane) -----------------------
  const float* zcbA = s_zcb[ia];
  const float* zcbB = s_zcb[ib];
  const float2 zpA = ((const float2*)zcbA)[lane];
  const float2 zpB = ((const float2*)zcbB)[lane];
  const float z0A = zpA.x, z1A = zpA.y;
  const float z0B = zpB.x, z1B = zpB.y;
  const float z2A = zcbA[(lane == 63) ? 127 : (2*lane + 2)];
  const float z2B = zcbB[(lane == 63) ? 127 : (2*lane + 2)];
  const float d0A = z1A - z0A;
  const float d0B = z1B - z0B;
  const float d1A = (lane == 63) ? 1e10f : (z2A - z1A);
  const float d1B = (lane == 63) ? 1e10f : (z2B - z1B);

  const float s0A = fmaxf(sgfA.x, 0.0f), s1A = fmaxf(sgfA.y, 0.0f);
  const float s0B = fmaxf(sgfB.x, 0.0f), s1B = fmaxf(sgfB.y, 0.0f);
  const float a0A = 1.0f - __expf(-d0A * s0A);
  const float a1A = 1.0f - __expf(-d1A * s1A);
  const float a0B = 1.0f - __expf(-d0B * s0B);
  const float a1B = 1.0f - __expf(-d1B * s1B);
  const float t0A = 1.0f - a0A + 1e-10f, t1A = 1.0f - a1A + 1e-10f;
  const float t0B = 1.0f - a0B + 1e-10f, t1B = 1.0f - a1B + 1e-10f;

  const float ppA  = scan_mul64(t0A * t1A);
  const float ppB  = scan_mul64(t0B * t1B);
  const float PexA = WAVE_SR1(1.0f, ppA);
  const float PexB = WAVE_SR1(1.0f, ppB);
  const float w0A = a0A * PexA;
  const float w1A = a1A * PexA * t0A;
  const float w0B = a0B * PexB;
  const float w1B = a1B * PexB * t0B;

  const float fRA = scan_add64(w0A * cA0.x + w1A * cA1.y);
  const float fRB = scan_add64(w0B * cB0.x + w1B * cB1.y);
  const float fGA = scan_add64(w0A * cA0.y + w1A * cA2.x);
  const float fGB = scan_add64(w0B * cB0.y + w1B * cB2.x);
  const float fBA = scan_add64(w0A * cA1.x + w1A * cA2.y);
  const float fBB = scan_add64(w0B * cB1.x + w1B * cB2.y);
  const float fDA = scan_add64(w0A * z0A  + w1A * z1A);
  const float fDB = scan_add64(w0B * z0B  + w1B * z1B);

  if (lane == 63) {
    // Telescope identity again: sum(w0+w1) = 1 - prod(t0*t1) + O(1e-8).
    const float fWA = 1.0f - ppA;
    const float fWB = 1.0f - ppB;
    out[n_rays*5 + rayA*3 + 0] = fRA + 1.0f - fWA;
    out[n_rays*5 + rayA*3 + 1] = fGA + 1.0f - fWA;
    out[n_rays*5 + rayA*3 + 2] = fBA + 1.0f - fWA;
    out[n_rays*8 + rayA]       = fWA;
    out[n_rays*9 + rayA]       = fDA + (1.0f - fWA) * farA;
    out[n_rays*5 + rayB*3 + 0] = fRB + 1.0f - fWB;
    out[n_rays*5 + rayB*3 + 1] = fGB + 1.0f - fWB;
    out[n_rays*5 + rayB*3 + 2] = fBB + 1.0f - fWB;
    out[n_rays*8 + rayB]       = fWB;
    out[n_rays*9 + rayB]       = fDB + (1.0f - fWB) * farB;
  }
}

extern "C" void kernel_launch(void* const* d_in, const int* in_sizes, int n_in,
                              void* d_out, int out_size, void* d_ws, size_t ws_size,
                              hipStream_t stream) {
  const float* rays = (const float*)d_in[0];
  const float* sigc = (const float*)d_in[1];
  const float* rgbc = (const float*)d_in[2];
  const float* sigf = (const float*)d_in[3];
  const float* rgbf = (const float*)d_in[4];
  float* out = (float*)d_out;
  const int n_rays = in_sizes[0] / 8;       // 131072
  const int blocks = n_rays / 8;            // 8 rays per 256-thread block (2/wave)
  nerf_volrend<<<blocks, 256, 0, stream>>>(rays, sigc, rgbc, sigf, rgbf, out, n_rays);
}